// Round 2
// baseline (192.466 us; speedup 1.0000x reference)
//
#include <hip/hip_runtime.h>

#define B_N 32768
#define D 512
#define NLEV 10
#define TM 128
#define TN 128
#define BK 32
#define MROWS_MAX 34048           // >= 32768 + 10*127, multiple of 128 and 256
#define MAX_RT (MROWS_MAX / TM)   // 266

typedef unsigned short u16;
typedef short s16x8 __attribute__((ext_vector_type(8)));
typedef u16 u16x8 __attribute__((ext_vector_type(8)));
typedef float f32x4 __attribute__((ext_vector_type(4)));

__device__ __forceinline__ u16 f2bf(float f) {
  union { float f; unsigned u; } v; v.f = f;
  unsigned r = v.u + 0x7fffu + ((v.u >> 16) & 1u);  // round-to-nearest-even
  return (u16)(r >> 16);
}

// ============================ BUCKET PATH (needs ~5.4 MB ws) ================

__global__ void k_prep(const float* __restrict__ lg, const float* __restrict__ attn,
                       float* __restrict__ coef, int* __restrict__ counts) {
  int t = threadIdx.x;
  if (t < NLEV) {
    float g[NLEV], a[NLEV];
    float mx = -1e30f;
    #pragma unroll
    for (int l = 0; l < NLEV; ++l) {
      g[l] = 1.0f / (1.0f + expf(-lg[l]));
      a[l] = attn[t * NLEV + l];
      mx = fmaxf(mx, a[l]);
    }
    float s = 0.0f;
    #pragma unroll
    for (int l = 0; l < NLEV; ++l) { a[l] = expf(a[l] - mx); s += a[l]; }
    float inv = 1.0f / s;
    #pragma unroll
    for (int l = 0; l < NLEV; ++l) {
      float c = 0.3f * a[l] * inv * g[l];
      if (l == t) c += 0.7f * g[t];
      coef[t * NLEV + l] = c;
    }
  }
  if (t >= 32 && t < 32 + NLEV) counts[t - 32] = 0;
}

__global__ void k_hist(const int* __restrict__ val, int* __restrict__ counts,
                       int* __restrict__ perm) {
  __shared__ int lc[NLEV];
  int t = threadIdx.x;
  int gid = blockIdx.x * 256 + t;
  if (t < NLEV) lc[t] = 0;
  __syncthreads();
  if (gid < B_N) {
    int v = val[gid]; v = v < 0 ? 0 : (v > NLEV - 1 ? NLEV - 1 : v);
    atomicAdd(&lc[v], 1);
  }
  if (gid < MROWS_MAX) perm[gid] = -1;
  __syncthreads();
  if (t < NLEV && lc[t] > 0) atomicAdd(&counts[t], lc[t]);
}

__global__ void k_scan(const int* __restrict__ counts, int* __restrict__ starts,
                       int* __restrict__ cursors) {
  if (threadIdx.x == 0 && blockIdx.x == 0) {
    int s = 0;
    for (int v = 0; v < NLEV; ++v) {
      starts[v] = s;
      cursors[v] = s;
      s += (counts[v] + TM - 1) & ~(TM - 1);
    }
    starts[NLEV] = s;
  }
}

__global__ void k_scatter(const int* __restrict__ val, int* __restrict__ cursors,
                          int* __restrict__ perm) {
  __shared__ int bcnt[NLEV], base[NLEV];
  int t = threadIdx.x;
  int gid = blockIdx.x * 256 + t;
  if (t < NLEV) bcnt[t] = 0;
  __syncthreads();
  int v = -1, pos = 0;
  if (gid < B_N) {
    v = val[gid]; v = v < 0 ? 0 : (v > NLEV - 1 ? NLEV - 1 : v);
    pos = atomicAdd(&bcnt[v], 1);
  }
  __syncthreads();
  if (t < NLEV && bcnt[t] > 0) base[t] = atomicAdd(&cursors[t], bcnt[t]);
  __syncthreads();
  if (v >= 0) perm[base[v] + pos] = gid;
}

__global__ void k_weff(const float* __restrict__ W, const float* __restrict__ coef,
                       u16* __restrict__ weff) {
  __shared__ float c[NLEV * NLEV];
  int t = threadIdx.x;
  if (t < NLEV * NLEV) c[t] = coef[t];
  __syncthreads();
  int idx = blockIdx.x * 256 + t;
  float w[NLEV];
  #pragma unroll
  for (int l = 0; l < NLEV; ++l) w[l] = W[l * (D * D) + idx];
  #pragma unroll
  for (int v = 0; v < NLEV; ++v) {
    float s = 0.0f;
    #pragma unroll
    for (int l = 0; l < NLEV; ++l) s += c[v * NLEV + l] * w[l];
    weff[v * (D * D) + idx] = f2bf(s);
  }
}

__global__ __launch_bounds__(256, 2) void k_gemm(
    const float* __restrict__ x, const u16* __restrict__ weff,
    const int* __restrict__ perm, const int* __restrict__ starts,
    const float* __restrict__ bias, float* __restrict__ out) {
  __shared__ u16 As[TM * BK];
  __shared__ u16 Bs[TN * BK];

  const int rt = blockIdx.y, ct = blockIdx.x;
  const int Mpad = starts[NLEV];
  if (rt * TM >= Mpad) return;

  int v = 0;
  #pragma unroll
  for (int i = 1; i < NLEV; ++i) if (rt * TM >= starts[i]) v = i;

  const int tid = threadIdx.x;
  const int lane = tid & 63, wave = tid >> 6;
  const int wm = (wave >> 1) * 64, wn = (wave & 1) * 64;
  const int fm = lane & 15;
  const int cb = lane >> 4;

  const int ar = tid >> 1;
  const int ah = tid & 1;
  int prow = perm[rt * TM + ar];
  if (prow < 0) prow = 0;
  const float* xrow = x + (size_t)prow * D + ah * 16;
  const int sw = (ar >> 1) & 3;

  const u16* wb = weff + ((size_t)v * D + ct * TN) * D;

  f32x4 acc[4][4];
  #pragma unroll
  for (int i = 0; i < 4; ++i)
    #pragma unroll
    for (int j = 0; j < 4; ++j) acc[i][j] = (f32x4){0.f, 0.f, 0.f, 0.f};

  for (int k0 = 0; k0 < D; k0 += BK) {
    #pragma unroll
    for (int j = 0; j < 2; ++j) {
      int c = j * 256 + wave * 64 + lane;
      int n_ = c >> 2, kc = c & 3;
      const u16* g = wb + n_ * D + k0 + kc * 8;
      __builtin_amdgcn_global_load_lds(
          (const __attribute__((address_space(1))) void*)g,
          (__attribute__((address_space(3))) void*)(Bs + (j * 256 + wave * 64) * 8),
          16, 0, 0);
    }
    const f32x4* xp = (const f32x4*)(xrow + k0);
    f32x4 f0 = xp[0], f1 = xp[1], f2 = xp[2], f3 = xp[3];
    u16x8 c0, c1;
    #pragma unroll
    for (int q = 0; q < 4; ++q) {
      c0[q] = f2bf(f0[q]); c0[4 + q] = f2bf(f1[q]);
      c1[q] = f2bf(f2[q]); c1[4 + q] = f2bf(f3[q]);
    }
    *(u16x8*)(As + ar * BK + (((ah * 2 + 0) ^ sw) << 3)) = c0;
    *(u16x8*)(As + ar * BK + (((ah * 2 + 1) ^ sw) << 3)) = c1;
    __syncthreads();

    s16x8 af[4], bf[4];
    #pragma unroll
    for (int t = 0; t < 4; ++t) {
      int m = wm + t * 16 + fm;
      af[t] = *(const s16x8*)(As + m * BK + ((cb ^ ((m >> 1) & 3)) << 3));
      int n = wn + t * 16 + fm;
      bf[t] = *(const s16x8*)(Bs + n * BK + (cb << 3));
    }
    #pragma unroll
    for (int tm = 0; tm < 4; ++tm)
      #pragma unroll
      for (int tn = 0; tn < 4; ++tn)
        acc[tm][tn] = __builtin_amdgcn_mfma_f32_16x16x32_bf16(af[tm], bf[tn], acc[tm][tn], 0, 0, 0);
    __syncthreads();
  }

  float bv[4];
  #pragma unroll
  for (int tn = 0; tn < 4; ++tn) bv[tn] = bias[ct * TN + wn + tn * 16 + fm];
  #pragma unroll
  for (int tm = 0; tm < 4; ++tm) {
    #pragma unroll
    for (int r = 0; r < 4; ++r) {
      int mrow = wm + tm * 16 + (lane >> 4) * 4 + r;
      int p = perm[rt * TM + mrow];
      if (p >= 0) {
        float* o = out + (size_t)p * D + ct * TN + wn + fm;
        #pragma unroll
        for (int tn = 0; tn < 4; ++tn)
          o[tn * 16] = acc[tm][tn][r] + bv[tn];
      }
    }
  }
}

// ==================== FOLDED PATH (zero workspace, K = 5120) ================
// out[b,n] = sum_{l,k} c[v_b,l] * x[b,k] * W[l,n,k];  c computed in-block.

__global__ __launch_bounds__(256, 2) void k_gemm_folded(
    const float* __restrict__ x, const int* __restrict__ val,
    const float* __restrict__ W, const float* __restrict__ lg,
    const float* __restrict__ attn, const float* __restrict__ bias,
    float* __restrict__ out) {
  __shared__ u16 As[TM * BK];
  __shared__ u16 Bs[TN * BK];
  __shared__ float cf[NLEV * NLEV];

  const int tid = threadIdx.x;
  if (tid < NLEV) {
    float g[NLEV], a[NLEV];
    float mx = -1e30f;
    #pragma unroll
    for (int l = 0; l < NLEV; ++l) {
      g[l] = 1.0f / (1.0f + expf(-lg[l]));
      a[l] = attn[tid * NLEV + l];
      mx = fmaxf(mx, a[l]);
    }
    float s = 0.0f;
    #pragma unroll
    for (int l = 0; l < NLEV; ++l) { a[l] = expf(a[l] - mx); s += a[l]; }
    float inv = 1.0f / s;
    #pragma unroll
    for (int l = 0; l < NLEV; ++l) {
      float c = 0.3f * a[l] * inv * g[l];
      if (l == tid) c += 0.7f * g[tid];
      cf[tid * NLEV + l] = c;
    }
  }

  const int ct = blockIdx.x, mt = blockIdx.y;
  const int lane = tid & 63, wave = tid >> 6;
  const int wm = (wave >> 1) * 64, wn = (wave & 1) * 64;
  const int fm = lane & 15;
  const int cb = lane >> 4;
  const int ar = tid >> 1, ah = tid & 1;
  const int sw = (ar >> 1) & 3;

  const float* xrow = x + (size_t)(mt * TM + ar) * D + ah * 16;
  const float* wrow = W + (size_t)(ct * TN + ar) * D + ah * 16;
  int v = val[mt * TM + ar];
  v = v < 0 ? 0 : (v > NLEV - 1 ? NLEV - 1 : v);
  __syncthreads();   // cf ready

  f32x4 acc[4][4];
  #pragma unroll
  for (int i = 0; i < 4; ++i)
    #pragma unroll
    for (int j = 0; j < 4; ++j) acc[i][j] = (f32x4){0.f, 0.f, 0.f, 0.f};

  for (int l = 0; l < NLEV; ++l) {
    const float sc = cf[v * NLEV + l];
    const float* wl = wrow + (size_t)l * D * D;
    for (int kk = 0; kk < D; kk += BK) {
      // A: scaled x -> bf16, swizzled
      const f32x4* xp = (const f32x4*)(xrow + kk);
      f32x4 f0 = xp[0], f1 = xp[1], f2 = xp[2], f3 = xp[3];
      u16x8 c0, c1;
      #pragma unroll
      for (int q = 0; q < 4; ++q) {
        c0[q] = f2bf(sc * f0[q]); c0[4 + q] = f2bf(sc * f1[q]);
        c1[q] = f2bf(sc * f2[q]); c1[4 + q] = f2bf(sc * f3[q]);
      }
      *(u16x8*)(As + ar * BK + (((ah * 2 + 0) ^ sw) << 3)) = c0;
      *(u16x8*)(As + ar * BK + (((ah * 2 + 1) ^ sw) << 3)) = c1;
      // B: W level slice -> bf16, swizzled (row ar is the n index)
      const f32x4* wp = (const f32x4*)(wl + kk);
      f32x4 g0 = wp[0], g1 = wp[1], g2 = wp[2], g3 = wp[3];
      u16x8 d0, d1;
      #pragma unroll
      for (int q = 0; q < 4; ++q) {
        d0[q] = f2bf(g0[q]); d0[4 + q] = f2bf(g1[q]);
        d1[q] = f2bf(g2[q]); d1[4 + q] = f2bf(g3[q]);
      }
      *(u16x8*)(Bs + ar * BK + (((ah * 2 + 0) ^ sw) << 3)) = d0;
      *(u16x8*)(Bs + ar * BK + (((ah * 2 + 1) ^ sw) << 3)) = d1;
      __syncthreads();

      s16x8 af[4], bf[4];
      #pragma unroll
      for (int t = 0; t < 4; ++t) {
        int m = wm + t * 16 + fm;
        af[t] = *(const s16x8*)(As + m * BK + ((cb ^ ((m >> 1) & 3)) << 3));
        int n = wn + t * 16 + fm;
        bf[t] = *(const s16x8*)(Bs + n * BK + ((cb ^ ((n >> 1) & 3)) << 3));
      }
      #pragma unroll
      for (int tm = 0; tm < 4; ++tm)
        #pragma unroll
        for (int tn = 0; tn < 4; ++tn)
          acc[tm][tn] = __builtin_amdgcn_mfma_f32_16x16x32_bf16(af[tm], bf[tn], acc[tm][tn], 0, 0, 0);
      __syncthreads();
    }
  }

  float bv[4];
  #pragma unroll
  for (int tn = 0; tn < 4; ++tn) bv[tn] = bias[ct * TN + wn + tn * 16 + fm];
  #pragma unroll
  for (int tm = 0; tm < 4; ++tm) {
    #pragma unroll
    for (int r = 0; r < 4; ++r) {
      int mrow = mt * TM + wm + tm * 16 + (lane >> 4) * 4 + r;
      float* o = out + (size_t)mrow * D + ct * TN + wn + fm;
      #pragma unroll
      for (int tn = 0; tn < 4; ++tn)
        o[tn * 16] = acc[tm][tn][r] + bv[tn];
    }
  }
}

extern "C" void kernel_launch(void* const* d_in, const int* in_sizes, int n_in,
                              void* d_out, int out_size, void* d_ws, size_t ws_size,
                              hipStream_t stream) {
  const float* x    = (const float*)d_in[0];
  const int*   val  = (const int*)d_in[1];
  const float* W    = (const float*)d_in[2];
  const float* lg   = (const float*)d_in[3];
  const float* attn = (const float*)d_in[4];
  const float* bias = (const float*)d_in[5];
  float* out = (float*)d_out;

  const size_t REQ = 139264 + (size_t)NLEV * D * D * 2;  // 5,382,144 B

  if (d_ws != nullptr && ws_size >= REQ) {
    char* ws = (char*)d_ws;
    float* coef  = (float*)(ws + 0);
    int* counts  = (int*)(ws + 512);
    int* starts  = (int*)(ws + 1024);
    int* cursors = (int*)(ws + 1536);
    int* perm    = (int*)(ws + 2048);
    u16* weff    = (u16*)(ws + 139264);

    k_prep<<<1, 64, 0, stream>>>(lg, attn, coef, counts);
    k_hist<<<MROWS_MAX / 256, 256, 0, stream>>>(val, counts, perm);
    k_scan<<<1, 64, 0, stream>>>(counts, starts, cursors);
    k_scatter<<<B_N / 256, 256, 0, stream>>>(val, cursors, perm);
    k_weff<<<(D * D) / 256, 256, 0, stream>>>(W, coef, weff);
    k_gemm<<<dim3(D / TN, MAX_RT), 256, 0, stream>>>(x, weff, perm, starts, bias, out);
  } else {
    k_gemm_folded<<<dim3(D / TN, B_N / TM), 256, 0, stream>>>(
        x, val, W, lg, attn, bias, out);
  }
}

// Round 3
// 179.216 us; speedup vs baseline: 1.0739x; 1.0739x over previous
//
#include <hip/hip_runtime.h>

#define B_N 32768
#define D 512
#define DD (D * D)
#define NLEV 10
#define TM 128
#define TN 256
#define BK 32
#define NHB 128                   // histogram blocks (B_N / 256)
#define MROWS_MAX 34048           // 32768 + 10*128 padding headroom
#define MAX_RT (MROWS_MAX / TM)   // 266

typedef unsigned short u16;
typedef short s16x8 __attribute__((ext_vector_type(8)));
typedef u16 u16x8 __attribute__((ext_vector_type(8)));
typedef float f32x4 __attribute__((ext_vector_type(4)));

__device__ __forceinline__ u16 f2bf(float f) {
  union { float f; unsigned u; } v; v.f = f;
  unsigned r = v.u + 0x7fffu + ((v.u >> 16) & 1u);  // RNE
  return (u16)(r >> 16);
}
__device__ __forceinline__ int clampv(int v) {
  return v < 0 ? 0 : (v > NLEV - 1 ? NLEV - 1 : v);
}

// ---- K1: weff-build (blocks 0..1023) UNION hist+perm-fill (blocks 1024..1151)
__global__ void k1(const float* __restrict__ W, const float* __restrict__ lg,
                   const float* __restrict__ attn, const int* __restrict__ val,
                   u16* __restrict__ weff, u16* __restrict__ hist,
                   int* __restrict__ perm) {
  const int t = threadIdx.x;
  if (blockIdx.x < DD / 256) {
    // ---- weff role: coef computed in-block, then 10-level combine ----
    __shared__ float c[NLEV * NLEV];
    if (t < NLEV) {
      float g[NLEV], a[NLEV], mx = -1e30f;
      #pragma unroll
      for (int l = 0; l < NLEV; ++l) {
        g[l] = 1.0f / (1.0f + expf(-lg[l]));
        a[l] = attn[t * NLEV + l];
        mx = fmaxf(mx, a[l]);
      }
      float s = 0.f;
      #pragma unroll
      for (int l = 0; l < NLEV; ++l) { a[l] = expf(a[l] - mx); s += a[l]; }
      float inv = 1.0f / s;
      #pragma unroll
      for (int l = 0; l < NLEV; ++l) {
        float cc = 0.3f * a[l] * inv * g[l];
        if (l == t) cc += 0.7f * g[t];
        c[t * NLEV + l] = cc;
      }
    }
    __syncthreads();
    const int idx = blockIdx.x * 256 + t;
    float w[NLEV];
    #pragma unroll
    for (int l = 0; l < NLEV; ++l) w[l] = W[l * DD + idx];
    #pragma unroll
    for (int v = 0; v < NLEV; ++v) {
      float s = 0.f;
      #pragma unroll
      for (int l = 0; l < NLEV; ++l) s += c[v * NLEV + l] * w[l];
      weff[v * DD + idx] = f2bf(s);
    }
  } else {
    // ---- hist role: per-block histogram (no global atomics), perm := -1 ----
    __shared__ int lc[NLEV];
    const int b = blockIdx.x - DD / 256;   // 0..127
    if (t < NLEV) lc[t] = 0;
    __syncthreads();
    const int gid = b * 256 + t;
    atomicAdd(&lc[clampv(val[gid])], 1);
    perm[gid] = -1;
    if (b < (MROWS_MAX - B_N) / 256) perm[B_N + b * 256 + t] = -1;
    __syncthreads();
    if (t < NLEV) hist[b * NLEV + t] = (u16)lc[t];
  }
}

// ---- K2: deterministic counting-sort scatter (prefix over hist table) ------
__global__ void k2(const int* __restrict__ val, const u16* __restrict__ hist,
                   int* __restrict__ perm, int* __restrict__ starts) {
  __shared__ int h[NHB * NLEV];   // becomes exclusive per-block prefix in-place
  __shared__ int st[NLEV + 1];
  __shared__ int cnt[NLEV];
  __shared__ int lc[NLEV];
  const int t = threadIdx.x, b = blockIdx.x;
  for (int i = t; i < NHB * NLEV; i += 256) h[i] = hist[i];
  if (t < NLEV) lc[t] = 0;
  __syncthreads();
  if (t < NLEV) {
    int run = 0;
    for (int bb = 0; bb < NHB; ++bb) {
      int x = h[bb * NLEV + t];
      h[bb * NLEV + t] = run;
      run += x;
    }
    cnt[t] = run;
  }
  __syncthreads();
  if (t == 0) {
    int s = 0;
    for (int v = 0; v < NLEV; ++v) {
      st[v] = s;
      s += (cnt[v] + TM - 1) & ~(TM - 1);   // pad bucket to tile-M
    }
    st[NLEV] = s;
  }
  __syncthreads();
  const int gid = b * 256 + t;
  const int v = clampv(val[gid]);
  const int pos = atomicAdd(&lc[v], 1);    // LDS-only; intra-bucket order free
  perm[st[v] + h[b * NLEV + v] + pos] = gid;
  if (b == 0 && t <= NLEV) starts[t] = st[t];
}

// ---- K3: grouped GEMM, 128x256 tile, 8 waves, 16x16x32 bf16 MFMA ----------
__global__ __launch_bounds__(512, 4) void k3(
    const float* __restrict__ x, const u16* __restrict__ weff,
    const int* __restrict__ perm, const int* __restrict__ starts,
    const float* __restrict__ bias, float* __restrict__ out) {
  __shared__ u16 As[TM * BK];   // 8 KB,  [m][k], XOR-swizzled 16B chunks
  __shared__ u16 Bs[TN * BK];   // 16 KB, [n][k], XOR-swizzled via load source

  const int ct = blockIdx.x, rt = blockIdx.y;
  const int Mpad = starts[NLEV];
  if (rt * TM >= Mpad) return;

  int v = 0;
  #pragma unroll
  for (int i = 1; i < NLEV; ++i) if (rt * TM >= starts[i]) v = i;

  const int tid = threadIdx.x;
  const int lane = tid & 63, wave = tid >> 6;
  const int wm = (wave >> 2) * 64, wn = (wave & 3) * 64;
  const int fm = lane & 15;      // frag row/col within 16
  const int cb = lane >> 4;      // frag k-chunk (k = cb*8)

  // A staging: 4 threads per row, 8 floats (one 16B bf16 chunk) each
  const int ar = tid >> 2;       // 0..127
  const int ah = tid & 3;        // chunk 0..3
  int prow = perm[rt * TM + ar];
  if (prow < 0) prow = 0;
  const float* xrow = x + (size_t)prow * D + ah * 8;
  const int sw = (ar >> 1) & 3;

  const u16* wb = weff + ((size_t)v * D + ct * TN) * D;

  f32x4 acc[4][4];
  #pragma unroll
  for (int i = 0; i < 4; ++i)
    #pragma unroll
    for (int j = 0; j < 4; ++j) acc[i][j] = (f32x4){0.f, 0.f, 0.f, 0.f};

  for (int k0 = 0; k0 < D; k0 += BK) {
    // B tile: async global->LDS, 16B/lane; source k-chunk swizzled so that
    // LDS slot s of row n holds global chunk s ^ ((n>>1)&3)
    #pragma unroll
    for (int j = 0; j < 2; ++j) {
      const int c = j * 512 + wave * 64 + lane;  // chunk id = n*4 + slot
      const int n_ = c >> 2, slot = c & 3;
      const int kc = slot ^ ((n_ >> 1) & 3);
      const u16* g = wb + n_ * D + k0 + kc * 8;
      __builtin_amdgcn_global_load_lds(
          (const __attribute__((address_space(1))) void*)g,
          (__attribute__((address_space(3))) void*)(Bs + (j * 512 + wave * 64) * 8),
          16, 0, 0);
    }
    // A tile: fp32 load -> bf16 -> swizzled 16B LDS store
    const f32x4* xp = (const f32x4*)(xrow + k0);
    f32x4 f0 = xp[0], f1 = xp[1];
    u16x8 c0;
    #pragma unroll
    for (int q = 0; q < 4; ++q) { c0[q] = f2bf(f0[q]); c0[4 + q] = f2bf(f1[q]); }
    *(u16x8*)(As + ar * BK + ((ah ^ sw) << 3)) = c0;
    __syncthreads();

    s16x8 af[4], bf[4];
    #pragma unroll
    for (int t4 = 0; t4 < 4; ++t4) {
      const int m = wm + t4 * 16 + fm;
      af[t4] = *(const s16x8*)(As + m * BK + ((cb ^ ((m >> 1) & 3)) << 3));
      const int n = wn + t4 * 16 + fm;
      bf[t4] = *(const s16x8*)(Bs + n * BK + ((cb ^ ((n >> 1) & 3)) << 3));
    }
    #pragma unroll
    for (int tm = 0; tm < 4; ++tm)
      #pragma unroll
      for (int tn = 0; tn < 4; ++tn)
        acc[tm][tn] = __builtin_amdgcn_mfma_f32_16x16x32_bf16(af[tm], bf[tn], acc[tm][tn], 0, 0, 0);
    __syncthreads();
  }

  // Epilogue: C frag col=lane&15, row=(lane>>4)*4+reg; scatter rows via perm
  float bv[4];
  #pragma unroll
  for (int tn = 0; tn < 4; ++tn) bv[tn] = bias[ct * TN + wn + tn * 16 + fm];
  #pragma unroll
  for (int tm = 0; tm < 4; ++tm) {
    #pragma unroll
    for (int r = 0; r < 4; ++r) {
      const int mrow = wm + tm * 16 + (lane >> 4) * 4 + r;
      const int p = perm[rt * TM + mrow];
      if (p >= 0) {
        float* o = out + (size_t)p * D + ct * TN + wn + fm;
        #pragma unroll
        for (int tn = 0; tn < 4; ++tn)
          o[tn * 16] = acc[tm][tn][r] + bv[tn];
      }
    }
  }
}

extern "C" void kernel_launch(void* const* d_in, const int* in_sizes, int n_in,
                              void* d_out, int out_size, void* d_ws, size_t ws_size,
                              hipStream_t stream) {
  const float* x    = (const float*)d_in[0];
  const int*   val  = (const int*)d_in[1];
  const float* W    = (const float*)d_in[2];
  const float* lg   = (const float*)d_in[3];
  const float* attn = (const float*)d_in[4];
  const float* bias = (const float*)d_in[5];
  float* out = (float*)d_out;

  // ws layout (prefix < 139264 B, total 5,382,144 B — proven available in R2)
  char* ws = (char*)d_ws;
  int* starts = (int*)(ws + 0);          // 11 ints
  u16* hist   = (u16*)(ws + 64);         // 128*10 u16 = 2560 B
  int* perm   = (int*)(ws + 2688);       // 34048 ints -> ends 138880
  u16* weff   = (u16*)(ws + 139264);     // 10*512*512 bf16 = 5.24 MB

  k1<<<DD / 256 + NHB, 256, 0, stream>>>(W, lg, attn, val, weff, hist, perm);
  k2<<<NHB, 256, 0, stream>>>(val, hist, perm, starts);
  k3<<<dim3(D / TN, MAX_RT), 512, 0, stream>>>(x, weff, perm, starts, bias, out);
}

// Round 4
// 174.023 us; speedup vs baseline: 1.1060x; 1.0298x over previous
//
#include <hip/hip_runtime.h>

#define B_N 32768
#define D 512
#define DD (D * D)
#define NLEV 10
#define TM 128
#define TN 256
#define BK 32
#define NITER (D / BK)            // 16
#define NHB 128                   // histogram blocks (B_N / 256)
#define MROWS_MAX 34048           // 32768 + 10*128 padding headroom
#define MAX_RT (MROWS_MAX / TM)   // 266

typedef unsigned short u16;
typedef short s16x8 __attribute__((ext_vector_type(8)));
typedef u16 u16x8 __attribute__((ext_vector_type(8)));
typedef float f32x4 __attribute__((ext_vector_type(4)));

__device__ __forceinline__ u16 f2bf(float f) {
  union { float f; unsigned u; } v; v.f = f;
  unsigned r = v.u + 0x7fffu + ((v.u >> 16) & 1u);  // RNE
  return (u16)(r >> 16);
}
__device__ __forceinline__ int clampv(int v) {
  return v < 0 ? 0 : (v > NLEV - 1 ? NLEV - 1 : v);
}

// ---- K1: weff-build (blocks 0..1023) UNION hist+perm-fill (blocks 1024..1151)
__global__ void k1(const float* __restrict__ W, const float* __restrict__ lg,
                   const float* __restrict__ attn, const int* __restrict__ val,
                   u16* __restrict__ weff, u16* __restrict__ hist,
                   int* __restrict__ perm) {
  const int t = threadIdx.x;
  if (blockIdx.x < DD / 256) {
    __shared__ float c[NLEV * NLEV];
    if (t < NLEV) {
      float g[NLEV], a[NLEV], mx = -1e30f;
      #pragma unroll
      for (int l = 0; l < NLEV; ++l) {
        g[l] = 1.0f / (1.0f + expf(-lg[l]));
        a[l] = attn[t * NLEV + l];
        mx = fmaxf(mx, a[l]);
      }
      float s = 0.f;
      #pragma unroll
      for (int l = 0; l < NLEV; ++l) { a[l] = expf(a[l] - mx); s += a[l]; }
      float inv = 1.0f / s;
      #pragma unroll
      for (int l = 0; l < NLEV; ++l) {
        float cc = 0.3f * a[l] * inv * g[l];
        if (l == t) cc += 0.7f * g[t];
        c[t * NLEV + l] = cc;
      }
    }
    __syncthreads();
    const int idx = blockIdx.x * 256 + t;
    float w[NLEV];
    #pragma unroll
    for (int l = 0; l < NLEV; ++l) w[l] = W[l * DD + idx];
    #pragma unroll
    for (int v = 0; v < NLEV; ++v) {
      float s = 0.f;
      #pragma unroll
      for (int l = 0; l < NLEV; ++l) s += c[v * NLEV + l] * w[l];
      weff[v * DD + idx] = f2bf(s);
    }
  } else {
    __shared__ int lc[NLEV];
    const int b = blockIdx.x - DD / 256;   // 0..127
    if (t < NLEV) lc[t] = 0;
    __syncthreads();
    const int gid = b * 256 + t;
    atomicAdd(&lc[clampv(val[gid])], 1);
    perm[gid] = -1;
    if (b < (MROWS_MAX - B_N) / 256) perm[B_N + b * 256 + t] = -1;
    __syncthreads();
    if (t < NLEV) hist[b * NLEV + t] = (u16)lc[t];
  }
}

// ---- K2: deterministic counting-sort scatter (prefix over hist table) ------
__global__ void k2(const int* __restrict__ val, const u16* __restrict__ hist,
                   int* __restrict__ perm, int* __restrict__ starts) {
  __shared__ int h[NHB * NLEV];
  __shared__ int st[NLEV + 1];
  __shared__ int cnt[NLEV];
  __shared__ int lc[NLEV];
  const int t = threadIdx.x, b = blockIdx.x;
  for (int i = t; i < NHB * NLEV; i += 256) h[i] = hist[i];
  if (t < NLEV) lc[t] = 0;
  __syncthreads();
  if (t < NLEV) {
    int run = 0;
    for (int bb = 0; bb < NHB; ++bb) {
      int x = h[bb * NLEV + t];
      h[bb * NLEV + t] = run;
      run += x;
    }
    cnt[t] = run;
  }
  __syncthreads();
  if (t == 0) {
    int s = 0;
    for (int v = 0; v < NLEV; ++v) {
      st[v] = s;
      s += (cnt[v] + TM - 1) & ~(TM - 1);
    }
    st[NLEV] = s;
  }
  __syncthreads();
  const int gid = b * 256 + t;
  const int v = clampv(val[gid]);
  const int pos = atomicAdd(&lc[v], 1);
  perm[st[v] + h[b * NLEV + v] + pos] = gid;
  if (b == 0 && t <= NLEV) starts[t] = st[t];
}

// ---- K3: grouped GEMM, 128x256 tile, double-buffered K-loop ---------------
__global__ __launch_bounds__(512, 4) void k3(
    const float* __restrict__ x, const u16* __restrict__ weff,
    const int* __restrict__ perm, const int* __restrict__ starts,
    const float* __restrict__ bias, float* __restrict__ out) {
  __shared__ u16 As[2][TM * BK];   // 2 x 8 KB
  __shared__ u16 Bs[2][TN * BK];   // 2 x 16 KB

  const int ct = blockIdx.x, rt = blockIdx.y;
  const int Mpad = starts[NLEV];
  if (rt * TM >= Mpad) return;

  int v = 0;
  #pragma unroll
  for (int i = 1; i < NLEV; ++i) if (rt * TM >= starts[i]) v = i;

  const int tid = threadIdx.x;
  const int lane = tid & 63, wave = tid >> 6;
  const int wm = (wave >> 2) * 64, wn = (wave & 3) * 64;
  const int fm = lane & 15;
  const int cb = lane >> 4;

  // A staging: 4 threads per row, 8 floats (one 16B bf16 chunk) each
  const int ar = tid >> 2;       // 0..127
  const int ah = tid & 3;        // chunk 0..3
  int prow = perm[rt * TM + ar];
  if (prow < 0) prow = 0;
  const float* xrow = x + (size_t)prow * D + ah * 8;
  const int sw = (ar >> 1) & 3;
  const int aslot = ar * BK + ((ah ^ sw) << 3);

  const u16* wb = weff + ((size_t)v * D + ct * TN) * D;
  // B staging source addresses (two 16B chunks per thread), swizzled at source
  const int c0i = wave * 64 + lane;            // chunk id = n*4 + slot
  const int c1i = 512 + c0i;
  const int n0 = c0i >> 2, s0 = c0i & 3, kc0 = s0 ^ ((n0 >> 1) & 3);
  const int n1 = c1i >> 2, s1 = c1i & 3, kc1 = s1 ^ ((n1 >> 1) & 3);
  const u16* gb0 = wb + n0 * D + kc0 * 8;
  const u16* gb1 = wb + n1 * D + kc1 * 8;
  const int bdst0 = c0i * 8, bdst1 = c1i * 8;

  f32x4 acc[4][4];
  #pragma unroll
  for (int i = 0; i < 4; ++i)
    #pragma unroll
    for (int j = 0; j < 4; ++j) acc[i][j] = (f32x4){0.f, 0.f, 0.f, 0.f};

  // ---- prologue: stage iter 0, reg-prefetch x for iter 1 ----
  {
    __builtin_amdgcn_global_load_lds(
        (const __attribute__((address_space(1))) void*)gb0,
        (__attribute__((address_space(3))) void*)(Bs[0] + bdst0), 16, 0, 0);
    __builtin_amdgcn_global_load_lds(
        (const __attribute__((address_space(1))) void*)gb1,
        (__attribute__((address_space(3))) void*)(Bs[0] + bdst1), 16, 0, 0);
    const f32x4* xp = (const f32x4*)xrow;
    f32x4 f0 = xp[0], f1 = xp[1];
    u16x8 cc;
    #pragma unroll
    for (int q = 0; q < 4; ++q) { cc[q] = f2bf(f0[q]); cc[4 + q] = f2bf(f1[q]); }
    *(u16x8*)(As[0] + aslot) = cc;
  }
  f32x4 cf0, cf1;   // x data for iter i+1 (loaded 2 iters ahead of LDS-use)
  {
    const f32x4* xp = (const f32x4*)(xrow + BK);
    cf0 = xp[0]; cf1 = xp[1];
  }
  __syncthreads();

  int p = 0;
  for (int i = 0; i < NITER; ++i) {
    const bool hn = (i + 1 < NITER);
    // issue B prefetch for iter i+1 into buffer p^1
    if (hn) {
      const int k1o = (i + 1) * BK;
      __builtin_amdgcn_global_load_lds(
          (const __attribute__((address_space(1))) void*)(gb0 + k1o),
          (__attribute__((address_space(3))) void*)(Bs[p ^ 1] + bdst0), 16, 0, 0);
      __builtin_amdgcn_global_load_lds(
          (const __attribute__((address_space(1))) void*)(gb1 + k1o),
          (__attribute__((address_space(3))) void*)(Bs[p ^ 1] + bdst1), 16, 0, 0);
    }
    // issue x load for iter i+2
    f32x4 nf0, nf1;
    if (i + 2 < NITER) {
      const f32x4* xp = (const f32x4*)(xrow + (i + 2) * BK);
      nf0 = xp[0]; nf1 = xp[1];
    }
    // compute on buffer p (overlaps in-flight loads)
    s16x8 af[4], bf[4];
    #pragma unroll
    for (int t4 = 0; t4 < 4; ++t4) {
      const int m = wm + t4 * 16 + fm;
      af[t4] = *(const s16x8*)(As[p] + m * BK + ((cb ^ ((m >> 1) & 3)) << 3));
      const int n = wn + t4 * 16 + fm;
      bf[t4] = *(const s16x8*)(Bs[p] + n * BK + ((cb ^ ((n >> 1) & 3)) << 3));
    }
    #pragma unroll
    for (int tm = 0; tm < 4; ++tm)
      #pragma unroll
      for (int tn = 0; tn < 4; ++tn)
        acc[tm][tn] = __builtin_amdgcn_mfma_f32_16x16x32_bf16(af[tm], bf[tn], acc[tm][tn], 0, 0, 0);
    // convert + LDS-write the x chunk for iter i+1 (loaded 2 iters ago)
    if (hn) {
      u16x8 cc;
      #pragma unroll
      for (int q = 0; q < 4; ++q) { cc[q] = f2bf(cf0[q]); cc[4 + q] = f2bf(cf1[q]); }
      *(u16x8*)(As[p ^ 1] + aslot) = cc;
      cf0 = nf0; cf1 = nf1;
    }
    __syncthreads();
    p ^= 1;
  }

  // Epilogue: C frag col=lane&15, row=(lane>>4)*4+reg; scatter rows via perm
  float bv[4];
  #pragma unroll
  for (int tn = 0; tn < 4; ++tn) bv[tn] = bias[ct * TN + wn + tn * 16 + fm];
  #pragma unroll
  for (int tm = 0; tm < 4; ++tm) {
    #pragma unroll
    for (int r = 0; r < 4; ++r) {
      const int mrow = wm + tm * 16 + (lane >> 4) * 4 + r;
      const int p2 = perm[rt * TM + mrow];
      if (p2 >= 0) {
        float* o = out + (size_t)p2 * D + ct * TN + wn + fm;
        #pragma unroll
        for (int tn = 0; tn < 4; ++tn)
          o[tn * 16] = acc[tm][tn][r] + bv[tn];
      }
    }
  }
}

extern "C" void kernel_launch(void* const* d_in, const int* in_sizes, int n_in,
                              void* d_out, int out_size, void* d_ws, size_t ws_size,
                              hipStream_t stream) {
  const float* x    = (const float*)d_in[0];
  const int*   val  = (const int*)d_in[1];
  const float* W    = (const float*)d_in[2];
  const float* lg   = (const float*)d_in[3];
  const float* attn = (const float*)d_in[4];
  const float* bias = (const float*)d_in[5];
  float* out = (float*)d_out;

  char* ws = (char*)d_ws;
  int* starts = (int*)(ws + 0);          // 11 ints
  u16* hist   = (u16*)(ws + 64);         // 128*10 u16
  int* perm   = (int*)(ws + 2688);       // 34048 ints -> ends 138880
  u16* weff   = (u16*)(ws + 139264);     // 10*512*512 bf16 = 5.24 MB

  k1<<<DD / 256 + NHB, 256, 0, stream>>>(W, lg, attn, val, weff, hist, perm);
  k2<<<NHB, 256, 0, stream>>>(val, hist, perm, starts);
  k3<<<dim3(D / TN, MAX_RT), 512, 0, stream>>>(x, weff, perm, starts, bias, out);
}